// Round 15
// baseline (173.110 us; speedup 1.0000x reference)
//
#include <hip/hip_runtime.h>

#define N_NODES    50000
#define N_EDGES    800000
#define DIM        128
#define NUM_GRAPHS 512
#define BN_EPS     1e-5f

#define NBUCK      196                // buckets of 256 nodes: dst >> 8
#define CAP        4608               // per-bucket capacity (mean 4096 + 8 sigma)
#define NBINS      4096               // (dst_local << 4) | src_slice (src>>12)
#define TILE       4096               // edges per partitionA block (512 threads)
#define MLP_ROWS   128                // rows per fused_mlp block (512 threads, 8 waves)
#define POOL_SPLIT 4                  // blocks per graph in graph_pool

typedef unsigned int u32;
typedef unsigned short u16;
typedef __attribute__((ext_vector_type(8))) short bf16x8;
typedef __attribute__((ext_vector_type(4))) float f32x4;

__device__ __forceinline__ u16 f2bf(float f) {
    u32 u = __float_as_uint(f);
    u += 0x7FFF + ((u >> 16) & 1);    // round-to-nearest-even
    return (u16)(u >> 16);
}
__device__ __forceinline__ float bf2f(u16 h) {
    return __uint_as_float((u32)h << 16);
}

// ---- merged prep: [0,256) wt frag | [256,1280) x->bf16 | [1280,1344) zeros --
__global__ __launch_bounds__(256)
void prep_kernel(const float* __restrict__ x, const float* __restrict__ W1,
                 const float* __restrict__ W2, u16* __restrict__ hx,
                 u16* __restrict__ wt, float* __restrict__ zreg,
                 float* __restrict__ out_pool)
{
    if (blockIdx.x < 256) {
        // weight fragment order: [m][c][kk][lane][e];
        // element = W_m[k = kk*32 + (lane>>4)*8 + e][j = c*16 + (lane&15)]
        int idx = blockIdx.x * 256 + threadIdx.x;   // 0..65535
        int m    = idx >> 14;
        int f    = idx & 16383;
        int c    = (f >> 11) & 7;
        int kk   = (f >> 9) & 3;
        int lane = (f >> 3) & 63;
        int e    = f & 7;
        int k = kk * 32 + ((lane >> 4) << 3) + e;
        int j = c * 16 + (lane & 15);
        const float* src = (m & 1) ? W2 : W1;
        src += (m >> 1) * 128 * 128;
        wt[idx] = f2bf(src[k * 128 + j]);
    } else if (blockIdx.x < 1280) {
        const long long n4 = (long long)N_NODES * DIM / 4;
        long long stride = 1024LL * 256;
        for (long long i = (blockIdx.x - 256) * 256LL + threadIdx.x; i < n4; i += stride) {
            float4 v = ((const float4*)x)[i];
            ushort4 o;
            o.x = f2bf(v.x); o.y = f2bf(v.y); o.z = f2bf(v.z); o.w = f2bf(v.w);
            ((ushort4*)hx)[i] = o;
        }
    } else {
        // zero: stats0|stats1|gCursor (768 words) + out_pool (65536 words)
        int stride = 64 * 256;
        for (int i = (blockIdx.x - 1280) * 256 + threadIdx.x;
             i < 768 + NUM_GRAPHS * DIM; i += stride) {
            if (i < 768) zreg[i] = 0.f;
            else         out_pool[i - 768] = 0.f;
        }
    }
}

// ------- partition A: append tiles into fixed-capacity bucket regions --------
__global__ __launch_bounds__(512)
void partitionA(const int* __restrict__ src, const int* __restrict__ dst,
                const float* __restrict__ ew, int* __restrict__ gCursor,
                uint2* __restrict__ ed2)
{
    __shared__ int cnt[NBUCK];
    __shared__ int off[NBUCK];
    __shared__ int gb[NBUCK];
    __shared__ u32 stg_sw[TILE];
    __shared__ u32 stg_d[TILE];
    __shared__ int scanb[256];

    const int t = threadIdx.x;
    const int base = blockIdx.x * TILE;
    const int tcnt = min(TILE, N_EDGES - base);

    if (t < NBUCK) cnt[t] = 0;
    __syncthreads();

    u32 swv[8], dv[8];
    int rk[8], bk[8];
    #pragma unroll
    for (int j = 0; j < 8; ++j) {
        int e = base + j * 512 + t;
        if (e < N_EDGES) {
            int d = dst[e];
            swv[j] = ((u32)f2bf(ew[e]) << 16) | (u32)src[e];
            dv[j]  = (u32)d;
            bk[j]  = d >> 8;
            rk[j]  = atomicAdd(&cnt[bk[j]], 1);
        } else bk[j] = -1;
    }
    __syncthreads();

    // exclusive scan of tile cnt -> off
    {
        int v = (t < NBUCK) ? cnt[t] : 0;
        if (t < 256) scanb[t] = v;
        __syncthreads();
        for (int o = 1; o < 256; o <<= 1) {
            int x = (t < 256 && t >= o) ? scanb[t - o] : 0;
            __syncthreads();
            if (t < 256) scanb[t] += x;
            __syncthreads();
        }
        if (t < NBUCK) off[t] = scanb[t] - v;
    }
    __syncthreads();

    #pragma unroll
    for (int j = 0; j < 8; ++j) {
        if (bk[j] >= 0) {
            int idx = off[bk[j]] + rk[j];
            stg_sw[idx] = swv[j];
            stg_d[idx]  = dv[j];
        }
    }
    if (t < NBUCK && cnt[t] > 0) gb[t] = atomicAdd(&gCursor[t], cnt[t]);
    __syncthreads();

    for (int j = t; j < tcnt; j += 512) {
        u32 d = stg_d[j];
        int b = (int)(d >> 8);
        long long pos = (long long)b * CAP + gb[b] + (j - off[b]);
        ed2[pos] = make_uint2(stg_sw[j], d);
    }
}

// ------- partition B: per-(node, src-slice-16) CSR within bucket + rowptr -----
__global__ __launch_bounds__(256)
void partitionB(const uint2* __restrict__ ed2, const int* __restrict__ gCursor,
                int* __restrict__ rowptr, u32* __restrict__ ed)
{
    __shared__ int bstart[256];
    __shared__ int hist[NBINS];     // 16 KB
    __shared__ int cursor[NBINS];   // 16 KB
    __shared__ int sc[256];

    const int b = blockIdx.x;
    const int t = threadIdx.x;

    // exclusive scan of final bucket totals -> bstart
    {
        int v = (t < NBUCK) ? gCursor[t] : 0;
        sc[t] = v;
        __syncthreads();
        for (int o = 1; o < 256; o <<= 1) {
            int x = (t >= o) ? sc[t - o] : 0;
            __syncthreads();
            sc[t] += x;
            __syncthreads();
        }
        bstart[t] = sc[t] - v;
    }
    __syncthreads();

    const int s0 = bstart[b];
    const int n  = gCursor[b];
    const uint2* srcp = ed2 + (long long)b * CAP;

    #pragma unroll
    for (int q = 0; q < 16; ++q) hist[t + q * 256] = 0;
    __syncthreads();
    for (int j = t; j < n; j += 256) {
        uint2 r = srcp[j];
        int bin = (int)((r.y & 255u) << 4) | (int)((r.x & 0xFFFFu) >> 12);
        atomicAdd(&hist[bin], 1);
    }
    __syncthreads();

    // hierarchical exclusive scan over 4096 bins (16 bins / thread)
    int loc[16]; int sum = 0;
    #pragma unroll
    for (int q = 0; q < 16; ++q) { loc[q] = hist[t * 16 + q]; sum += loc[q]; }
    sc[t] = sum;
    __syncthreads();
    for (int o = 1; o < 256; o <<= 1) {
        int x = (t >= o) ? sc[t - o] : 0;
        __syncthreads();
        sc[t] += x;
        __syncthreads();
    }
    int run = sc[t] - sum;                 // exclusive prefix at bin t*16
    rowptr[b * 256 + t] = s0 + run;        // node t's row start
    #pragma unroll
    for (int q = 0; q < 16; ++q) {
        cursor[t * 16 + q] = s0 + run;
        run += loc[q];
    }
    __syncthreads();

    for (int j = t; j < n; j += 256) {
        uint2 r = srcp[j];
        int bin = (int)((r.y & 255u) << 4) | (int)((r.x & 0xFFFFu) >> 12);
        int p = atomicAdd(&cursor[bin], 1);
        ed[p] = r.x;
    }
}

// ------------- pull-gather SpMM: 16 lanes/node, prefetched edge batches ------
template<bool BN>
__global__ __launch_bounds__(256)
void gather_spmm(const u16* __restrict__ h, const u32* __restrict__ ed,
                 const int* __restrict__ rowptr, u16* __restrict__ pooled,
                 const float* __restrict__ stats, const float* __restrict__ gamma,
                 const float* __restrict__ beta)
{
    __shared__ float scs[128];
    __shared__ float shs[128];
    if (BN) {
        if (threadIdx.x < 128) {
            int c = threadIdx.x;
            float mu  = stats[c] * (1.f / N_NODES);
            float var = stats[128 + c] * (1.f / N_NODES) - mu * mu;
            float s   = gamma[c] * rsqrtf(var + BN_EPS);
            scs[c] = s;
            shs[c] = beta[c] - mu * s;
        }
        __syncthreads();
    }

    int node = blockIdx.x * 16 + (threadIdx.x >> 4);  // 16 nodes per block
    int lane = threadIdx.x & 15;                      // 16 threads per node
    int beg = rowptr[node];
    int end = rowptr[node + 1];

    float sc8[8], sh8[8];
    if (BN) {
        #pragma unroll
        for (int q = 0; q < 8; ++q) {
            sc8[q] = scs[lane * 8 + q];
            sh8[q] = shs[lane * 8 + q];
        }
    }

    float acc[8];
    #pragma unroll
    for (int q = 0; q < 8; ++q) acc[q] = 0.f;

    u32 sw_cur = (beg + lane < end) ? ed[beg + lane] : 0u;
    for (int base = beg; base < end; base += 16) {
        u32 sw_next = (base + 16 + lane < end) ? ed[base + 16 + lane] : 0u;
        int cnt = min(16, end - base);
        #pragma unroll 4
        for (int i = 0; i < cnt; ++i) {
            u32 rec = __shfl(sw_cur, i, 16);
            long long s = (long long)(rec & 0xFFFFu);
            float w = bf2f((u16)(rec >> 16));
            bf16x8 hv = *((const bf16x8*)(h + (s << 7)) + lane);
            #pragma unroll
            for (int q = 0; q < 8; ++q) {
                float v = bf2f((u16)hv[q]);
                if (BN) v = fmaxf(v * sc8[q] + sh8[q], 0.f);
                acc[q] += w * v;
            }
        }
        sw_cur = sw_next;
    }
    bf16x8 o;
    #pragma unroll
    for (int q = 0; q < 8; ++q) o[q] = (short)f2bf(acc[q]);
    *((bf16x8*)(pooled + ((long long)node << 7)) + lane) = o;
}

// ---------------- fused MFMA MLP v4: weights streamed from L2, hid-only LDS --
// Weights in fragment order -> each (c,kk) read is a wave-coalesced 1KB load;
// 64KB weight set is L2-resident. LDS = 32KB hid + 1KB stats -> 3 blocks/CU.
__global__ __launch_bounds__(512, 6)
void fused_mlp(const u16* __restrict__ A, const u16* __restrict__ wtL,
               const float* __restrict__ b1, const float* __restrict__ b2,
               u16* __restrict__ Z, float* __restrict__ stats)
{
    __shared__ __align__(16) u16 hid[16384];   // 32 KB
    __shared__ float ssum[128];
    __shared__ float ssq[128];

    const int tid  = threadIdx.x;
    const int lane = tid & 63;
    const int wave = tid >> 6;             // 0..7
    const int l15  = lane & 15;
    const int lk   = lane >> 4;            // 0..3
    const int row0 = blockIdx.x * MLP_ROWS;
    const int wrow = wave * 16;

    if (tid < 128) { ssum[tid] = 0.f; ssq[tid] = 0.f; }
    __syncthreads();                       // (1) stats init visible

    const bf16x8* w1g = (const bf16x8*)wtL;       // 2048 fragment chunks
    const bf16x8* w2g = w1g + 2048;

    // A-fragments from global
    bf16x8 afr[4];
    {
        int rg = row0 + wrow + l15;
        bool ok = rg < N_NODES;
        const u16* ap = A + (long long)rg * 128 + lk * 8;
        bf16x8 zero = {};
        #pragma unroll
        for (int kk = 0; kk < 4; ++kk)
            afr[kk] = ok ? *(const bf16x8*)(ap + kk * 32) : zero;
    }

    // GEMM1: weights streamed (L2), 8 c-blocks in registers
    f32x4 acc1[8];
    #pragma unroll
    for (int c = 0; c < 8; ++c) {
        float bv = b1[c * 16 + l15];
        f32x4 a = {bv, bv, bv, bv};
        #pragma unroll
        for (int kk = 0; kk < 4; ++kk) {
            bf16x8 w = w1g[(c * 4 + kk) * 64 + lane];
            a = __builtin_amdgcn_mfma_f32_16x16x32_bf16(afr[kk], w, a, 0, 0, 0);
        }
        acc1[c] = a;
    }

    // hid (relu, bf16) into own wave's LDS rows, XOR-swizzled (wave-local)
    #pragma unroll
    for (int c = 0; c < 8; ++c) {
        #pragma unroll
        for (int i = 0; i < 4; ++i) {
            int row = wrow + lk * 4 + i;
            int col = c * 16 + l15;
            hid[row * 128 + (col ^ ((row & 15) << 3))] = f2bf(fmaxf(acc1[c][i], 0.f));
        }
    }

    // GEMM2 A-fragments from own wave's hid rows (wave-local, no barrier)
    bf16x8 afr2[4];
    {
        int row = wrow + l15;
        #pragma unroll
        for (int kk = 0; kk < 4; ++kk)
            afr2[kk] = *(bf16x8*)&hid[row * 128 + ((kk * 32 + lk * 8) ^ ((row & 15) << 3))];
    }

    // GEMM2 + stats; z (bf16) back into own hid rows for coalesced store
    #pragma unroll
    for (int c = 0; c < 8; ++c) {
        float bv = b2[c * 16 + l15];
        f32x4 a = {bv, bv, bv, bv};
        #pragma unroll
        for (int kk = 0; kk < 4; ++kk) {
            bf16x8 w = w2g[(c * 4 + kk) * 64 + lane];
            a = __builtin_amdgcn_mfma_f32_16x16x32_bf16(afr2[kk], w, a, 0, 0, 0);
        }
        float s = 0.f, sq = 0.f;
        #pragma unroll
        for (int i = 0; i < 4; ++i) {
            int row = wrow + lk * 4 + i;
            int rg  = row0 + row;
            float v = a[i];
            bool ok = rg < N_NODES;
            if (ok) { s += v; sq += v * v; }
            hid[row * 128 + ((c * 16 + l15) ^ ((row & 15) << 3))] = ok ? f2bf(v) : (u16)0;
        }
        s  += __shfl_xor(s, 16);  s  += __shfl_xor(s, 32);
        sq += __shfl_xor(sq, 16); sq += __shfl_xor(sq, 32);
        if (lk == 0) {
            atomicAdd(&ssum[c * 16 + l15], s);
            atomicAdd(&ssq[c * 16 + l15], sq);
        }
    }

    // wave-local coalesced z store (own 16 rows, 4 x b128 per lane)
    #pragma unroll
    for (int j = 0; j < 4; ++j) {
        int chunk = j * 64 + lane;         // 0..255
        int rl  = chunk >> 4;
        int c8  = chunk & 15;
        int row = wrow + rl;
        int rg  = row0 + row;
        if (rg < N_NODES) {
            bf16x8 v = *(bf16x8*)&hid[row * 128 + ((c8 * 8) ^ ((row & 15) << 3))];
            *(bf16x8*)(Z + (long long)rg * 128 + c8 * 8) = v;
        }
    }
    __syncthreads();                       // (2) all LDS stat adds done
    if (tid < 128) {
        atomicAdd(&stats[tid], ssum[tid]);
        atomicAdd(&stats[128 + tid], ssq[tid]);
    }
}

// --------- graph pooling fused with BN+relu of layer-1 z ----------------------
__global__ __launch_bounds__(256)
void graph_pool_bn(const u16* __restrict__ z, const float* __restrict__ stats,
                   const float* __restrict__ gamma, const float* __restrict__ beta,
                   const int* __restrict__ gid, const float* __restrict__ pw,
                   float* __restrict__ out_nodes, float* __restrict__ out_pool)
{
    __shared__ float scs[128];
    __shared__ float shs[128];
    if (threadIdx.x < 128) {
        int c = threadIdx.x;
        float mu  = stats[c] * (1.f / N_NODES);
        float var = stats[128 + c] * (1.f / N_NODES) - mu * mu;
        float s   = gamma[c] * rsqrtf(var + BN_EPS);
        scs[c] = s;
        shs[c] = beta[c] - mu * s;
    }
    __syncthreads();

    int g    = blockIdx.x >> 2;            // POOL_SPLIT = 4
    int part = blockIdx.x & 3;

    int lo = 0, hi = N_NODES;
    while (lo < hi) { int m = (lo + hi) >> 1; if (gid[m] < g) lo = m + 1; else hi = m; }
    int start = lo;
    hi = N_NODES;
    while (lo < hi) { int m = (lo + hi) >> 1; if (gid[m] < g + 1) lo = m + 1; else hi = m; }
    int end = lo;

    int len  = end - start;
    int qlen = (len + 3) >> 2;
    int s = start + part * qlen;
    int e = min(end, s + qlen);

    const int t  = threadIdx.x;
    const int rg = t >> 5;
    const int c4 = t & 31;
    float4 sc4 = *(float4*)&scs[c4 * 4];
    float4 sh4 = *(float4*)&shs[c4 * 4];

    float4 acc = make_float4(0.f, 0.f, 0.f, 0.f);
    for (int r = s + rg; r < e; r += 8) {
        float w = pw[r];
        ushort4 hv = *((const ushort4*)(z + (long long)r * DIM) + c4);
        float4 v;
        v.x = fmaxf(bf2f(hv.x) * sc4.x + sh4.x, 0.f);
        v.y = fmaxf(bf2f(hv.y) * sc4.y + sh4.y, 0.f);
        v.z = fmaxf(bf2f(hv.z) * sc4.z + sh4.z, 0.f);
        v.w = fmaxf(bf2f(hv.w) * sc4.w + sh4.w, 0.f);
        *((float4*)(out_nodes + (long long)r * DIM) + c4) = v;
        acc.x += w * v.x; acc.y += w * v.y;
        acc.z += w * v.z; acc.w += w * v.w;
    }

    __shared__ float4 sd[256];
    sd[t] = acc;
    __syncthreads();
    if (t < 32) {
        float4 tot = sd[t];
        #pragma unroll
        for (int i = 1; i < 8; ++i) {
            float4 v = sd[i * 32 + t];
            tot.x += v.x; tot.y += v.y; tot.z += v.z; tot.w += v.w;
        }
        float* op = out_pool + g * DIM + t * 4;
        atomicAdd(op + 0, tot.x);
        atomicAdd(op + 1, tot.y);
        atomicAdd(op + 2, tot.z);
        atomicAdd(op + 3, tot.w);
    }
}

extern "C" void kernel_launch(void* const* d_in, const int* in_sizes, int n_in,
                              void* d_out, int out_size, void* d_ws, size_t ws_size,
                              hipStream_t stream)
{
    const float* x    = (const float*)d_in[0];
    const int*   esrc = (const int*)d_in[1];
    const int*   edst = (const int*)d_in[2];
    const float* ew   = (const float*)d_in[3];
    const int*   gid  = (const int*)d_in[4];
    const float* pw   = (const float*)d_in[5];
    const float* W1   = (const float*)d_in[6];
    const float* b1   = (const float*)d_in[7];
    const float* W2   = (const float*)d_in[8];
    const float* b2   = (const float*)d_in[9];
    const float* gam  = (const float*)d_in[10];
    const float* bet  = (const float*)d_in[11];

    float* out_pool  = (float*)d_out;                      // [512,128]
    float* out_nodes = (float*)d_out + NUM_GRAPHS * DIM;   // [50000,128]

    // ---- workspace layout ----
    const size_t NF = (size_t)N_NODES * DIM;
    char* w = (char*)d_ws;
    u32*   ed       = (u32*)w;        w += (size_t)N_EDGES * sizeof(u32);
    u16*   pooledBf = (u16*)w;        w += NF * sizeof(u16);   // aliases ed2cap
    u16*   zBf      = (u16*)w;        w += NF * sizeof(u16);
    u16*   hx       = (u16*)w;        w += NF * sizeof(u16);
    u16*   wt       = (u16*)w;        w += (size_t)4 * 128 * 128 * sizeof(u16);
    // contiguous zero region: stats0 | stats1 | gCursor (768 words)
    float* stats0   = (float*)w;      w += 256 * sizeof(float);
    float* stats1   = (float*)w;      w += 256 * sizeof(float);
    int*   gCursor  = (int*)w;        w += 256 * sizeof(int);
    int*   rowptr   = (int*)w;        w += (NBUCK * 256 + 64) * sizeof(int);

    // ed2cap (196 * 4608 * 8B = 7.2MB) aliases pooledBf's 12.8MB region:
    // written by partitionA, consumed by partitionB, dead before first gather.
    uint2* ed2cap   = (uint2*)pooledBf;

    const int mlpGrid    = (N_NODES + MLP_ROWS - 1) / MLP_ROWS;  // 391
    const int gatherGrid = (N_NODES + 15) / 16;          // 3125
    const int partGrid   = (N_EDGES + TILE - 1) / TILE;  // 196

    // ---- prep (wt frag + x cvt + zero fills) + CSR build ----
    prep_kernel<<<1344, 256, 0, stream>>>(x, W1, W2, hx, wt, stats0, out_pool);
    partitionA<<<partGrid, 512, 0, stream>>>(esrc, edst, ew, gCursor, ed2cap);
    partitionB<<<NBUCK, 256, 0, stream>>>(ed2cap, gCursor, rowptr, ed);

    // ---- layer 0 ----
    gather_spmm<false><<<gatherGrid, 256, 0, stream>>>(hx, ed, rowptr, pooledBf,
                                                       nullptr, nullptr, nullptr);
    fused_mlp<<<mlpGrid, 512, 0, stream>>>(pooledBf, wt, b1, b2, zBf, stats0);

    // ---- layer 1 (BN of layer-0 z fused into the gather) ----
    gather_spmm<true><<<gatherGrid, 256, 0, stream>>>(zBf, ed, rowptr, pooledBf,
                                                      stats0, gam, bet);
    fused_mlp<<<mlpGrid, 512, 0, stream>>>(pooledBf, wt + 32768,
                                           b1 + DIM, b2 + DIM, zBf, stats1);

    // ---- BN(layer-1) + node output + graph pooling, all fused ----
    graph_pool_bn<<<NUM_GRAPHS * POOL_SPLIT, 256, 0, stream>>>(
        zBf, stats1, gam + DIM, bet + DIM, gid, pw, out_nodes, out_pool);
}

// Round 16
// 152.778 us; speedup vs baseline: 1.1331x; 1.1331x over previous
//
#include <hip/hip_runtime.h>

#define N_NODES    50000
#define N_EDGES    800000
#define DIM        128
#define NUM_GRAPHS 512
#define BN_EPS     1e-5f

#define NBUCK      196                // buckets of 256 nodes: dst >> 8
#define CAP        4608               // per-bucket capacity (mean 4096 + 8 sigma)
#define NBINS      2048               // (dst_local << 3) | src_slice (src>>13)
#define TILE       4096               // edges per partitionA block (512 threads)
#define MLP_ROWS   128                // rows per fused_mlp block (512 threads, 8 waves)
#define POOL_SPLIT 4                  // blocks per graph in graph_pool

typedef unsigned int u32;
typedef unsigned short u16;
typedef __attribute__((ext_vector_type(8))) short bf16x8;
typedef __attribute__((ext_vector_type(4))) float f32x4;

__device__ __forceinline__ u16 f2bf(float f) {
    u32 u = __float_as_uint(f);
    u += 0x7FFF + ((u >> 16) & 1);    // round-to-nearest-even
    return (u16)(u >> 16);
}
__device__ __forceinline__ float bf2f(u16 h) {
    return __uint_as_float((u32)h << 16);
}

// ---- merged prep: [0,256) wt frag | [256,1280) x->bf16 | [1280,1344) zeros --
__global__ __launch_bounds__(256)
void prep_kernel(const float* __restrict__ x, const float* __restrict__ W1,
                 const float* __restrict__ W2, u16* __restrict__ hx,
                 u16* __restrict__ wt, float* __restrict__ zreg,
                 float* __restrict__ out_pool)
{
    if (blockIdx.x < 256) {
        // weight fragment order: [m][c][kk][lane][e];
        // element = W_m[k = kk*32 + (lane>>4)*8 + e][j = c*16 + (lane&15)]
        int idx = blockIdx.x * 256 + threadIdx.x;   // 0..65535
        int m    = idx >> 14;
        int f    = idx & 16383;
        int c    = (f >> 11) & 7;
        int kk   = (f >> 9) & 3;
        int lane = (f >> 3) & 63;
        int e    = f & 7;
        int k = kk * 32 + ((lane >> 4) << 3) + e;
        int j = c * 16 + (lane & 15);
        const float* src = (m & 1) ? W2 : W1;
        src += (m >> 1) * 128 * 128;
        wt[idx] = f2bf(src[k * 128 + j]);
    } else if (blockIdx.x < 1280) {
        const long long n4 = (long long)N_NODES * DIM / 4;
        long long stride = 1024LL * 256;
        for (long long i = (blockIdx.x - 256) * 256LL + threadIdx.x; i < n4; i += stride) {
            float4 v = ((const float4*)x)[i];
            ushort4 o;
            o.x = f2bf(v.x); o.y = f2bf(v.y); o.z = f2bf(v.z); o.w = f2bf(v.w);
            ((ushort4*)hx)[i] = o;
        }
    } else {
        // zero: stats0|stats1|gCursor (768 words) + out_pool (65536 words)
        int stride = 64 * 256;
        for (int i = (blockIdx.x - 1280) * 256 + threadIdx.x;
             i < 768 + NUM_GRAPHS * DIM; i += stride) {
            if (i < 768) zreg[i] = 0.f;
            else         out_pool[i - 768] = 0.f;
        }
    }
}

// ------- partition A: append tiles into fixed-capacity bucket regions --------
__global__ __launch_bounds__(512)
void partitionA(const int* __restrict__ src, const int* __restrict__ dst,
                const float* __restrict__ ew, int* __restrict__ gCursor,
                uint2* __restrict__ ed2)
{
    __shared__ int cnt[NBUCK];
    __shared__ int off[NBUCK];
    __shared__ int gb[NBUCK];
    __shared__ u32 stg_sw[TILE];
    __shared__ u32 stg_d[TILE];
    __shared__ int scanb[256];

    const int t = threadIdx.x;
    const int base = blockIdx.x * TILE;
    const int tcnt = min(TILE, N_EDGES - base);

    if (t < NBUCK) cnt[t] = 0;
    __syncthreads();

    u32 swv[8], dv[8];
    int rk[8], bk[8];
    #pragma unroll
    for (int j = 0; j < 8; ++j) {
        int e = base + j * 512 + t;
        if (e < N_EDGES) {
            int d = dst[e];
            swv[j] = ((u32)f2bf(ew[e]) << 16) | (u32)src[e];
            dv[j]  = (u32)d;
            bk[j]  = d >> 8;
            rk[j]  = atomicAdd(&cnt[bk[j]], 1);
        } else bk[j] = -1;
    }
    __syncthreads();

    // exclusive scan of tile cnt -> off
    {
        int v = (t < NBUCK) ? cnt[t] : 0;
        if (t < 256) scanb[t] = v;
        __syncthreads();
        for (int o = 1; o < 256; o <<= 1) {
            int x = (t < 256 && t >= o) ? scanb[t - o] : 0;
            __syncthreads();
            if (t < 256) scanb[t] += x;
            __syncthreads();
        }
        if (t < NBUCK) off[t] = scanb[t] - v;
    }
    __syncthreads();

    #pragma unroll
    for (int j = 0; j < 8; ++j) {
        if (bk[j] >= 0) {
            int idx = off[bk[j]] + rk[j];
            stg_sw[idx] = swv[j];
            stg_d[idx]  = dv[j];
        }
    }
    if (t < NBUCK && cnt[t] > 0) gb[t] = atomicAdd(&gCursor[t], cnt[t]);
    __syncthreads();

    for (int j = t; j < tcnt; j += 512) {
        u32 d = stg_d[j];
        int b = (int)(d >> 8);
        long long pos = (long long)b * CAP + gb[b] + (j - off[b]);
        ed2[pos] = make_uint2(stg_sw[j], d);
    }
}

// ------- partition B: per-(node, src-slice) CSR within bucket + rowptr --------
// Bins edges by (dst_local, src>>13) so each node's edge list is ordered by
// src slice (7 x ~2MB slices) -> gather's h reads get XCD-L2 locality.
__global__ __launch_bounds__(256)
void partitionB(const uint2* __restrict__ ed2, const int* __restrict__ gCursor,
                int* __restrict__ rowptr, u32* __restrict__ ed)
{
    __shared__ int bstart[256];
    __shared__ int hist[NBINS];
    __shared__ int cursor[NBINS];
    __shared__ int sc[256];

    const int b = blockIdx.x;
    const int t = threadIdx.x;

    // exclusive scan of final bucket totals -> bstart
    {
        int v = (t < NBUCK) ? gCursor[t] : 0;
        sc[t] = v;
        __syncthreads();
        for (int o = 1; o < 256; o <<= 1) {
            int x = (t >= o) ? sc[t - o] : 0;
            __syncthreads();
            sc[t] += x;
            __syncthreads();
        }
        bstart[t] = sc[t] - v;
    }
    __syncthreads();

    const int s0 = bstart[b];
    const int n  = gCursor[b];
    const uint2* srcp = ed2 + (long long)b * CAP;

    #pragma unroll
    for (int q = 0; q < 8; ++q) hist[t + q * 256] = 0;
    __syncthreads();
    for (int j = t; j < n; j += 256) {
        uint2 r = srcp[j];
        int bin = (int)((r.y & 255u) << 3) | (int)((r.x & 0xFFFFu) >> 13);
        atomicAdd(&hist[bin], 1);
    }
    __syncthreads();

    // hierarchical exclusive scan over 2048 bins (8 bins / thread)
    int loc[8]; int sum = 0;
    #pragma unroll
    for (int q = 0; q < 8; ++q) { loc[q] = hist[t * 8 + q]; sum += loc[q]; }
    sc[t] = sum;
    __syncthreads();
    for (int o = 1; o < 256; o <<= 1) {
        int x = (t >= o) ? sc[t - o] : 0;
        __syncthreads();
        sc[t] += x;
        __syncthreads();
    }
    int run = sc[t] - sum;                 // exclusive prefix at bin t*8
    rowptr[b * 256 + t] = s0 + run;        // node t's row start
    #pragma unroll
    for (int q = 0; q < 8; ++q) {
        cursor[t * 8 + q] = s0 + run;
        run += loc[q];
    }
    __syncthreads();

    for (int j = t; j < n; j += 256) {
        uint2 r = srcp[j];
        int bin = (int)((r.y & 255u) << 3) | (int)((r.x & 0xFFFFu) >> 13);
        int p = atomicAdd(&cursor[bin], 1);
        ed[p] = r.x;
    }
}

// ------------- pull-gather SpMM: 16 lanes/node, prefetched edge batches ------
template<bool BN>
__global__ __launch_bounds__(256)
void gather_spmm(const u16* __restrict__ h, const u32* __restrict__ ed,
                 const int* __restrict__ rowptr, u16* __restrict__ pooled,
                 const float* __restrict__ stats, const float* __restrict__ gamma,
                 const float* __restrict__ beta)
{
    __shared__ float scs[128];
    __shared__ float shs[128];
    if (BN) {
        if (threadIdx.x < 128) {
            int c = threadIdx.x;
            float mu  = stats[c] * (1.f / N_NODES);
            float var = stats[128 + c] * (1.f / N_NODES) - mu * mu;
            float s   = gamma[c] * rsqrtf(var + BN_EPS);
            scs[c] = s;
            shs[c] = beta[c] - mu * s;
        }
        __syncthreads();
    }

    int node = blockIdx.x * 16 + (threadIdx.x >> 4);  // 16 nodes per block
    int lane = threadIdx.x & 15;                      // 16 threads per node
    int beg = rowptr[node];
    int end = rowptr[node + 1];

    float sc8[8], sh8[8];
    if (BN) {
        #pragma unroll
        for (int q = 0; q < 8; ++q) {
            sc8[q] = scs[lane * 8 + q];
            sh8[q] = shs[lane * 8 + q];
        }
    }

    float acc[8];
    #pragma unroll
    for (int q = 0; q < 8; ++q) acc[q] = 0.f;

    u32 sw_cur = (beg + lane < end) ? ed[beg + lane] : 0u;
    for (int base = beg; base < end; base += 16) {
        u32 sw_next = (base + 16 + lane < end) ? ed[base + 16 + lane] : 0u;
        int cnt = min(16, end - base);
        #pragma unroll 4
        for (int i = 0; i < cnt; ++i) {
            u32 rec = __shfl(sw_cur, i, 16);
            long long s = (long long)(rec & 0xFFFFu);
            float w = bf2f((u16)(rec >> 16));
            bf16x8 hv = *((const bf16x8*)(h + (s << 7)) + lane);
            #pragma unroll
            for (int q = 0; q < 8; ++q) {
                float v = bf2f((u16)hv[q]);
                if (BN) v = fmaxf(v * sc8[q] + sh8[q], 0.f);
                acc[q] += w * v;
            }
        }
        sw_cur = sw_next;
    }
    bf16x8 o;
    #pragma unroll
    for (int q = 0; q < 8; ++q) o[q] = (short)f2bf(acc[q]);
    *((bf16x8*)(pooled + ((long long)node << 7)) + lane) = o;
}

// ---------------- fused MFMA MLP (3 barriers, fragment-order weights) ---------
__global__ __launch_bounds__(512)
void fused_mlp(const u16* __restrict__ A, const u16* __restrict__ wtL,
               const float* __restrict__ b1, const float* __restrict__ b2,
               u16* __restrict__ Z, float* __restrict__ stats)
{
    __shared__ __align__(16) u16 wfrag[32768];   // 64 KB
    __shared__ float ssum[128];
    __shared__ float ssq[128];

    const int tid  = threadIdx.x;
    const int lane = tid & 63;
    const int wave = tid >> 6;             // 0..7
    const int l15  = lane & 15;
    const int lk   = lane >> 4;            // 0..3
    const int row0 = blockIdx.x * MLP_ROWS;
    const int wrow = wave * 16;

    // stage BOTH weight matrices, coalesced fragment order (4096 x 16B)
    #pragma unroll
    for (int i = 0; i < 8; ++i) {
        int idx = tid + i * 512;
        *(bf16x8*)&wfrag[idx * 8] = *(const bf16x8*)(wtL + idx * 8);
    }
    if (tid < 128) { ssum[tid] = 0.f; ssq[tid] = 0.f; }

    // A-fragments from global
    bf16x8 afr[4];
    {
        int rg = row0 + wrow + l15;
        bool ok = rg < N_NODES;
        const u16* ap = A + (long long)rg * 128 + lk * 8;
        bf16x8 zero = {};
        #pragma unroll
        for (int kk = 0; kk < 4; ++kk)
            afr[kk] = ok ? *(const bf16x8*)(ap + kk * 32) : zero;
    }
    __syncthreads();                       // (1) weights staged

    // GEMM1: all 8 c-blocks accumulated in registers
    f32x4 acc1[8];
    #pragma unroll
    for (int c = 0; c < 8; ++c) {
        float bv = b1[c * 16 + l15];
        f32x4 a = {bv, bv, bv, bv};
        #pragma unroll
        for (int kk = 0; kk < 4; ++kk) {
            bf16x8 w = *(bf16x8*)&wfrag[((c * 4 + kk) * 64 + lane) * 8];
            a = __builtin_amdgcn_mfma_f32_16x16x32_bf16(afr[kk], w, a, 0, 0, 0);
        }
        acc1[c] = a;
    }
    __syncthreads();                       // (2) wt1 reads done -> region reusable

    // hid (relu, bf16) into overlay region, XOR-swizzled; wave-local
    #pragma unroll
    for (int c = 0; c < 8; ++c) {
        #pragma unroll
        for (int i = 0; i < 4; ++i) {
            int row = wrow + lk * 4 + i;
            int col = c * 16 + l15;
            wfrag[row * 128 + (col ^ ((row & 15) << 3))] = f2bf(fmaxf(acc1[c][i], 0.f));
        }
    }

    // GEMM2 A-fragments from own wave's hid rows (wave-local, no barrier)
    bf16x8 afr2[4];
    {
        int row = wrow + l15;
        #pragma unroll
        for (int kk = 0; kk < 4; ++kk)
            afr2[kk] = *(bf16x8*)&wfrag[row * 128 + ((kk * 32 + lk * 8) ^ ((row & 15) << 3))];
    }

    // GEMM2 + stats; z (bf16) back into own hid rows for coalesced store
    #pragma unroll
    for (int c = 0; c < 8; ++c) {
        float bv = b2[c * 16 + l15];
        f32x4 a = {bv, bv, bv, bv};
        #pragma unroll
        for (int kk = 0; kk < 4; ++kk) {
            bf16x8 w = *(bf16x8*)&wfrag[16384 + ((c * 4 + kk) * 64 + lane) * 8];
            a = __builtin_amdgcn_mfma_f32_16x16x32_bf16(afr2[kk], w, a, 0, 0, 0);
        }
        float s = 0.f, sq = 0.f;
        #pragma unroll
        for (int i = 0; i < 4; ++i) {
            int row = wrow + lk * 4 + i;
            int rg  = row0 + row;
            float v = a[i];
            bool ok = rg < N_NODES;
            if (ok) { s += v; sq += v * v; }
            wfrag[row * 128 + ((c * 16 + l15) ^ ((row & 15) << 3))] = ok ? f2bf(v) : (u16)0;
        }
        s  += __shfl_xor(s, 16);  s  += __shfl_xor(s, 32);
        sq += __shfl_xor(sq, 16); sq += __shfl_xor(sq, 32);
        if (lk == 0) {
            atomicAdd(&ssum[c * 16 + l15], s);
            atomicAdd(&ssq[c * 16 + l15], sq);
        }
    }

    // wave-local coalesced z store (own 16 rows, 4 x b128 per lane)
    #pragma unroll
    for (int j = 0; j < 4; ++j) {
        int chunk = j * 64 + lane;         // 0..255
        int rl  = chunk >> 4;
        int c8  = chunk & 15;
        int row = wrow + rl;
        int rg  = row0 + row;
        if (rg < N_NODES) {
            bf16x8 v = *(bf16x8*)&wfrag[row * 128 + ((c8 * 8) ^ ((row & 15) << 3))];
            *(bf16x8*)(Z + (long long)rg * 128 + c8 * 8) = v;
        }
    }
    __syncthreads();                       // (3) all LDS stat adds done
    if (tid < 128) {
        atomicAdd(&stats[tid], ssum[tid]);
        atomicAdd(&stats[128 + tid], ssq[tid]);
    }
}

// --------- graph pooling fused with BN+relu of layer-1 z ----------------------
__global__ __launch_bounds__(256)
void graph_pool_bn(const u16* __restrict__ z, const float* __restrict__ stats,
                   const float* __restrict__ gamma, const float* __restrict__ beta,
                   const int* __restrict__ gid, const float* __restrict__ pw,
                   float* __restrict__ out_nodes, float* __restrict__ out_pool)
{
    __shared__ float scs[128];
    __shared__ float shs[128];
    if (threadIdx.x < 128) {
        int c = threadIdx.x;
        float mu  = stats[c] * (1.f / N_NODES);
        float var = stats[128 + c] * (1.f / N_NODES) - mu * mu;
        float s   = gamma[c] * rsqrtf(var + BN_EPS);
        scs[c] = s;
        shs[c] = beta[c] - mu * s;
    }
    __syncthreads();

    int g    = blockIdx.x >> 2;            // POOL_SPLIT = 4
    int part = blockIdx.x & 3;

    int lo = 0, hi = N_NODES;
    while (lo < hi) { int m = (lo + hi) >> 1; if (gid[m] < g) lo = m + 1; else hi = m; }
    int start = lo;
    hi = N_NODES;
    while (lo < hi) { int m = (lo + hi) >> 1; if (gid[m] < g + 1) lo = m + 1; else hi = m; }
    int end = lo;

    int len  = end - start;
    int qlen = (len + 3) >> 2;
    int s = start + part * qlen;
    int e = min(end, s + qlen);

    const int t  = threadIdx.x;
    const int rg = t >> 5;
    const int c4 = t & 31;
    float4 sc4 = *(float4*)&scs[c4 * 4];
    float4 sh4 = *(float4*)&shs[c4 * 4];

    float4 acc = make_float4(0.f, 0.f, 0.f, 0.f);
    for (int r = s + rg; r < e; r += 8) {
        float w = pw[r];
        ushort4 hv = *((const ushort4*)(z + (long long)r * DIM) + c4);
        float4 v;
        v.x = fmaxf(bf2f(hv.x) * sc4.x + sh4.x, 0.f);
        v.y = fmaxf(bf2f(hv.y) * sc4.y + sh4.y, 0.f);
        v.z = fmaxf(bf2f(hv.z) * sc4.z + sh4.z, 0.f);
        v.w = fmaxf(bf2f(hv.w) * sc4.w + sh4.w, 0.f);
        *((float4*)(out_nodes + (long long)r * DIM) + c4) = v;
        acc.x += w * v.x; acc.y += w * v.y;
        acc.z += w * v.z; acc.w += w * v.w;
    }

    __shared__ float4 sd[256];
    sd[t] = acc;
    __syncthreads();
    if (t < 32) {
        float4 tot = sd[t];
        #pragma unroll
        for (int i = 1; i < 8; ++i) {
            float4 v = sd[i * 32 + t];
            tot.x += v.x; tot.y += v.y; tot.z += v.z; tot.w += v.w;
        }
        float* op = out_pool + g * DIM + t * 4;
        atomicAdd(op + 0, tot.x);
        atomicAdd(op + 1, tot.y);
        atomicAdd(op + 2, tot.z);
        atomicAdd(op + 3, tot.w);
    }
}

extern "C" void kernel_launch(void* const* d_in, const int* in_sizes, int n_in,
                              void* d_out, int out_size, void* d_ws, size_t ws_size,
                              hipStream_t stream)
{
    const float* x    = (const float*)d_in[0];
    const int*   esrc = (const int*)d_in[1];
    const int*   edst = (const int*)d_in[2];
    const float* ew   = (const float*)d_in[3];
    const int*   gid  = (const int*)d_in[4];
    const float* pw   = (const float*)d_in[5];
    const float* W1   = (const float*)d_in[6];
    const float* b1   = (const float*)d_in[7];
    const float* W2   = (const float*)d_in[8];
    const float* b2   = (const float*)d_in[9];
    const float* gam  = (const float*)d_in[10];
    const float* bet  = (const float*)d_in[11];

    float* out_pool  = (float*)d_out;                      // [512,128]
    float* out_nodes = (float*)d_out + NUM_GRAPHS * DIM;   // [50000,128]

    // ---- workspace layout ----
    const size_t NF = (size_t)N_NODES * DIM;
    char* w = (char*)d_ws;
    u32*   ed       = (u32*)w;        w += (size_t)N_EDGES * sizeof(u32);
    u16*   pooledBf = (u16*)w;        w += NF * sizeof(u16);   // aliases ed2cap
    u16*   zBf      = (u16*)w;        w += NF * sizeof(u16);
    u16*   hx       = (u16*)w;        w += NF * sizeof(u16);
    u16*   wt       = (u16*)w;        w += (size_t)4 * 128 * 128 * sizeof(u16);
    // contiguous zero region: stats0 | stats1 | gCursor (768 words)
    float* stats0   = (float*)w;      w += 256 * sizeof(float);
    float* stats1   = (float*)w;      w += 256 * sizeof(float);
    int*   gCursor  = (int*)w;        w += 256 * sizeof(int);
    int*   rowptr   = (int*)w;        w += (NBUCK * 256 + 64) * sizeof(int);

    // ed2cap (196 * 4608 * 8B = 7.2MB) aliases pooledBf's 12.8MB region:
    // written by partitionA, consumed by partitionB, dead before first gather.
    uint2* ed2cap   = (uint2*)pooledBf;

    const int mlpGrid    = (N_NODES + MLP_ROWS - 1) / MLP_ROWS;  // 391
    const int gatherGrid = (N_NODES + 15) / 16;          // 3125
    const int partGrid   = (N_EDGES + TILE - 1) / TILE;  // 196

    // ---- prep (wt frag + x cvt + zero fills) + CSR build ----
    prep_kernel<<<1344, 256, 0, stream>>>(x, W1, W2, hx, wt, stats0, out_pool);
    partitionA<<<partGrid, 512, 0, stream>>>(esrc, edst, ew, gCursor, ed2cap);
    partitionB<<<NBUCK, 256, 0, stream>>>(ed2cap, gCursor, rowptr, ed);

    // ---- layer 0 ----
    gather_spmm<false><<<gatherGrid, 256, 0, stream>>>(hx, ed, rowptr, pooledBf,
                                                       nullptr, nullptr, nullptr);
    fused_mlp<<<mlpGrid, 512, 0, stream>>>(pooledBf, wt, b1, b2, zBf, stats0);

    // ---- layer 1 (BN of layer-0 z fused into the gather) ----
    gather_spmm<true><<<gatherGrid, 256, 0, stream>>>(zBf, ed, rowptr, pooledBf,
                                                      stats0, gam, bet);
    fused_mlp<<<mlpGrid, 512, 0, stream>>>(pooledBf, wt + 32768,
                                           b1 + DIM, b2 + DIM, zBf, stats1);

    // ---- BN(layer-1) + node output + graph pooling, all fused ----
    graph_pool_bn<<<NUM_GRAPHS * POOL_SPLIT, 256, 0, stream>>>(
        zBf, stats1, gam + DIM, bet + DIM, gid, pw, out_nodes, out_pool);
}

// Round 17
// 152.653 us; speedup vs baseline: 1.1340x; 1.0008x over previous
//
#include <hip/hip_runtime.h>

#define N_NODES    50000
#define N_EDGES    800000
#define DIM        128
#define NUM_GRAPHS 512
#define BN_EPS     1e-5f

#define NBUCK      196                // buckets of 256 nodes: dst >> 8
#define CAP        4608               // per-bucket capacity (mean 4096 + 8 sigma)
#define NBINS      2048               // (dst_local << 3) | src_slice (src>>13)
#define TILE       4096               // edges per partitionA block-range block
#define MLP_ROWS   128                // rows per fused_mlp block (512 threads, 8 waves)
#define POOL_SPLIT 4                  // blocks per graph in graph_pool

// merged prep+partA block ranges
#define RA_N       196                // partitionA blocks [0,196)
#define RX_N       512                // x->bf16 blocks
#define RW_N       128                // wt frag blocks
#define RZ_N       32                 // zero blocks
#define RTOTAL     (RA_N + RX_N + RW_N + RZ_N)   // 868

typedef unsigned int u32;
typedef unsigned short u16;
typedef __attribute__((ext_vector_type(8))) short bf16x8;
typedef __attribute__((ext_vector_type(4))) float f32x4;

__device__ __forceinline__ u16 f2bf(float f) {
    u32 u = __float_as_uint(f);
    u += 0x7FFF + ((u >> 16) & 1);    // round-to-nearest-even
    return (u16)(u >> 16);
}
__device__ __forceinline__ float bf2f(u16 h) {
    return __uint_as_float((u32)h << 16);
}

// ---- tiny pre-fill: gCursor only (must be zero before partA range runs) -----
__global__ __launch_bounds__(256)
void fill_cursor_kernel(int* __restrict__ gCursor)
{
    gCursor[threadIdx.x] = 0;
}

// ==== merged prep + partitionA ================================================
// [0,196): partitionA tiles | [196,708): x->bf16 | [708,836): wt frag |
// [836,868): zero stats+out_pool.  partA first: it's on the critical path.
__global__ __launch_bounds__(512)
void prep_partA(const float* __restrict__ x, const float* __restrict__ W1,
                const float* __restrict__ W2, const int* __restrict__ src,
                const int* __restrict__ dst, const float* __restrict__ ew,
                u16* __restrict__ hx, u16* __restrict__ wt,
                float* __restrict__ zreg, float* __restrict__ out_pool,
                int* __restrict__ gCursor, uint2* __restrict__ ed2)
{
    // union LDS (sized for partA, largest user)
    __shared__ __align__(16) char smem[36992];

    const int t = threadIdx.x;

    if (blockIdx.x < RA_N) {
        // ---------------- partitionA tile ----------------
        int* cnt   = (int*)smem;                       // 196
        int* off   = cnt + NBUCK;                      // 196
        int* gb    = off + NBUCK;                      // 196
        int* scanb = gb + NBUCK;                       // 256
        u32* stg_sw = (u32*)(scanb + 256);             // 4096
        u32* stg_d  = stg_sw + TILE;                   // 4096

        const int base = blockIdx.x * TILE;
        const int tcnt = min(TILE, N_EDGES - base);

        if (t < NBUCK) cnt[t] = 0;
        __syncthreads();

        u32 swv[8], dv[8];
        int rk[8], bk[8];
        #pragma unroll
        for (int j = 0; j < 8; ++j) {
            int e = base + j * 512 + t;
            if (e < N_EDGES) {
                int d = dst[e];
                swv[j] = ((u32)f2bf(ew[e]) << 16) | (u32)src[e];
                dv[j]  = (u32)d;
                bk[j]  = d >> 8;
                rk[j]  = atomicAdd(&cnt[bk[j]], 1);
            } else bk[j] = -1;
        }
        __syncthreads();

        // exclusive scan of tile cnt -> off
        {
            int v = (t < NBUCK) ? cnt[t] : 0;
            if (t < 256) scanb[t] = v;
            __syncthreads();
            for (int o = 1; o < 256; o <<= 1) {
                int xv = (t < 256 && t >= o) ? scanb[t - o] : 0;
                __syncthreads();
                if (t < 256) scanb[t] += xv;
                __syncthreads();
            }
            if (t < NBUCK) off[t] = scanb[t] - v;
        }
        __syncthreads();

        #pragma unroll
        for (int j = 0; j < 8; ++j) {
            if (bk[j] >= 0) {
                int idx = off[bk[j]] + rk[j];
                stg_sw[idx] = swv[j];
                stg_d[idx]  = dv[j];
            }
        }
        if (t < NBUCK && cnt[t] > 0) gb[t] = atomicAdd(&gCursor[t], cnt[t]);
        __syncthreads();

        for (int j = t; j < tcnt; j += 512) {
            u32 d = stg_d[j];
            int b = (int)(d >> 8);
            long long pos = (long long)b * CAP + gb[b] + (j - off[b]);
            ed2[pos] = make_uint2(stg_sw[j], d);
        }
    } else if (blockIdx.x < RA_N + RX_N) {
        // ---------------- x -> bf16 ----------------
        const long long n4 = (long long)N_NODES * DIM / 4;
        long long stride = (long long)RX_N * 512;
        for (long long i = (blockIdx.x - RA_N) * 512LL + t; i < n4; i += stride) {
            float4 v = ((const float4*)x)[i];
            ushort4 o;
            o.x = f2bf(v.x); o.y = f2bf(v.y); o.z = f2bf(v.z); o.w = f2bf(v.w);
            ((ushort4*)hx)[i] = o;
        }
    } else if (blockIdx.x < RA_N + RX_N + RW_N) {
        // ---------------- weights -> bf16 fragment order ----------------
        // [m][c][kk][lane][e]; element = W_m[kk*32+(lane>>4)*8+e][c*16+(lane&15)]
        int idx = (blockIdx.x - RA_N - RX_N) * 512 + t;   // 0..65535
        int m    = idx >> 14;
        int f    = idx & 16383;
        int c    = (f >> 11) & 7;
        int kk   = (f >> 9) & 3;
        int lane = (f >> 3) & 63;
        int e    = f & 7;
        int k = kk * 32 + ((lane >> 4) << 3) + e;
        int j = c * 16 + (lane & 15);
        const float* srcw = (m & 1) ? W2 : W1;
        srcw += (m >> 1) * 128 * 128;
        wt[idx] = f2bf(srcw[k * 128 + j]);
    } else {
        // ---------------- zero stats (512 words) + out_pool ----------------
        int stride = RZ_N * 512;
        for (int i = (blockIdx.x - RA_N - RX_N - RW_N) * 512 + t;
             i < 512 + NUM_GRAPHS * DIM; i += stride) {
            if (i < 512) zreg[i] = 0.f;
            else         out_pool[i - 512] = 0.f;
        }
    }
}

// ------- partition B (512 thr): per-(node, src-slice) CSR + rowptr ------------
__global__ __launch_bounds__(512)
void partitionB(const uint2* __restrict__ ed2, const int* __restrict__ gCursor,
                int* __restrict__ rowptr, u32* __restrict__ ed)
{
    __shared__ int sc2[512];
    __shared__ int hist[NBINS];
    __shared__ int cursor[NBINS];

    const int b = blockIdx.x;
    const int t = threadIdx.x;

    // inclusive scan of bucket totals over 512 lanes (>=NBUCK zero-padded)
    int v = (t < NBUCK) ? gCursor[t] : 0;
    sc2[t] = v;
    __syncthreads();
    for (int o = 1; o < 512; o <<= 1) {
        int xv = (t >= o) ? sc2[t - o] : 0;
        __syncthreads();
        sc2[t] += xv;
        __syncthreads();
    }
    const int n  = gCursor[b];
    const int s0 = sc2[b] - n;
    __syncthreads();

    const uint2* srcp = ed2 + (long long)b * CAP;

    #pragma unroll
    for (int q = 0; q < 4; ++q) hist[t + q * 512] = 0;
    __syncthreads();
    for (int j = t; j < n; j += 512) {
        uint2 r = srcp[j];
        int bin = (int)((r.y & 255u) << 3) | (int)((r.x & 0xFFFFu) >> 13);
        atomicAdd(&hist[bin], 1);
    }
    __syncthreads();

    // hierarchical exclusive scan over 2048 bins (4 bins / thread, 512 lanes)
    int loc[4]; int sum = 0;
    #pragma unroll
    for (int q = 0; q < 4; ++q) { loc[q] = hist[t * 4 + q]; sum += loc[q]; }
    sc2[t] = sum;
    __syncthreads();
    for (int o = 1; o < 512; o <<= 1) {
        int xv = (t >= o) ? sc2[t - o] : 0;
        __syncthreads();
        sc2[t] += xv;
        __syncthreads();
    }
    int run = sc2[t] - sum;                // exclusive prefix at bin t*4
    if ((t & 1) == 0) rowptr[b * 256 + (t >> 1)] = s0 + run;  // node boundary (bin%8==0)
    #pragma unroll
    for (int q = 0; q < 4; ++q) {
        cursor[t * 4 + q] = s0 + run;
        run += loc[q];
    }
    __syncthreads();

    for (int j = t; j < n; j += 512) {
        uint2 r = srcp[j];
        int bin = (int)((r.y & 255u) << 3) | (int)((r.x & 0xFFFFu) >> 13);
        int p = atomicAdd(&cursor[bin], 1);
        ed[p] = r.x;
    }
}

// ------------- pull-gather SpMM: 16 lanes/node, prefetched edge batches ------
template<bool BN>
__global__ __launch_bounds__(256)
void gather_spmm(const u16* __restrict__ h, const u32* __restrict__ ed,
                 const int* __restrict__ rowptr, u16* __restrict__ pooled,
                 const float* __restrict__ stats, const float* __restrict__ gamma,
                 const float* __restrict__ beta)
{
    __shared__ float scs[128];
    __shared__ float shs[128];
    if (BN) {
        if (threadIdx.x < 128) {
            int c = threadIdx.x;
            float mu  = stats[c] * (1.f / N_NODES);
            float var = stats[128 + c] * (1.f / N_NODES) - mu * mu;
            float s   = gamma[c] * rsqrtf(var + BN_EPS);
            scs[c] = s;
            shs[c] = beta[c] - mu * s;
        }
        __syncthreads();
    }

    int node = blockIdx.x * 16 + (threadIdx.x >> 4);  // 16 nodes per block
    int lane = threadIdx.x & 15;                      // 16 threads per node
    int beg = rowptr[node];
    int end = rowptr[node + 1];

    float sc8[8], sh8[8];
    if (BN) {
        #pragma unroll
        for (int q = 0; q < 8; ++q) {
            sc8[q] = scs[lane * 8 + q];
            sh8[q] = shs[lane * 8 + q];
        }
    }

    float acc[8];
    #pragma unroll
    for (int q = 0; q < 8; ++q) acc[q] = 0.f;

    u32 sw_cur = (beg + lane < end) ? ed[beg + lane] : 0u;
    for (int base = beg; base < end; base += 16) {
        u32 sw_next = (base + 16 + lane < end) ? ed[base + 16 + lane] : 0u;
        int cnt = min(16, end - base);
        #pragma unroll 4
        for (int i = 0; i < cnt; ++i) {
            u32 rec = __shfl(sw_cur, i, 16);
            long long s = (long long)(rec & 0xFFFFu);
            float w = bf2f((u16)(rec >> 16));
            bf16x8 hv = *((const bf16x8*)(h + (s << 7)) + lane);
            #pragma unroll
            for (int q = 0; q < 8; ++q) {
                float v = bf2f((u16)hv[q]);
                if (BN) v = fmaxf(v * sc8[q] + sh8[q], 0.f);
                acc[q] += w * v;
            }
        }
        sw_cur = sw_next;
    }
    bf16x8 o;
    #pragma unroll
    for (int q = 0; q < 8; ++q) o[q] = (short)f2bf(acc[q]);
    *((bf16x8*)(pooled + ((long long)node << 7)) + lane) = o;
}

// ---------------- fused MFMA MLP (3 barriers, fragment-order weights) ---------
__global__ __launch_bounds__(512)
void fused_mlp(const u16* __restrict__ A, const u16* __restrict__ wtL,
               const float* __restrict__ b1, const float* __restrict__ b2,
               u16* __restrict__ Z, float* __restrict__ stats)
{
    __shared__ __align__(16) u16 wfrag[32768];   // 64 KB
    __shared__ float ssum[128];
    __shared__ float ssq[128];

    const int tid  = threadIdx.x;
    const int lane = tid & 63;
    const int wave = tid >> 6;             // 0..7
    const int l15  = lane & 15;
    const int lk   = lane >> 4;            // 0..3
    const int row0 = blockIdx.x * MLP_ROWS;
    const int wrow = wave * 16;

    // stage BOTH weight matrices, coalesced fragment order (4096 x 16B)
    #pragma unroll
    for (int i = 0; i < 8; ++i) {
        int idx = tid + i * 512;
        *(bf16x8*)&wfrag[idx * 8] = *(const bf16x8*)(wtL + idx * 8);
    }
    if (tid < 128) { ssum[tid] = 0.f; ssq[tid] = 0.f; }

    // A-fragments from global
    bf16x8 afr[4];
    {
        int rg = row0 + wrow + l15;
        bool ok = rg < N_NODES;
        const u16* ap = A + (long long)rg * 128 + lk * 8;
        bf16x8 zero = {};
        #pragma unroll
        for (int kk = 0; kk < 4; ++kk)
            afr[kk] = ok ? *(const bf16x8*)(ap + kk * 32) : zero;
    }
    __syncthreads();                       // (1) weights staged

    // GEMM1: all 8 c-blocks accumulated in registers
    f32x4 acc1[8];
    #pragma unroll
    for (int c = 0; c < 8; ++c) {
        float bv = b1[c * 16 + l15];
        f32x4 a = {bv, bv, bv, bv};
        #pragma unroll
        for (int kk = 0; kk < 4; ++kk) {
            bf16x8 w = *(bf16x8*)&wfrag[((c * 4 + kk) * 64 + lane) * 8];
            a = __builtin_amdgcn_mfma_f32_16x16x32_bf16(afr[kk], w, a, 0, 0, 0);
        }
        acc1[c] = a;
    }
    __syncthreads();                       // (2) wt1 reads done -> region reusable

    // hid (relu, bf16) into overlay region, XOR-swizzled; wave-local
    #pragma unroll
    for (int c = 0; c < 8; ++c) {
        #pragma unroll
        for (int i = 0; i < 4; ++i) {
            int row = wrow + lk * 4 + i;
            int col = c * 16 + l15;
            wfrag[row * 128 + (col ^ ((row & 15) << 3))] = f2bf(fmaxf(acc1[c][i], 0.f));
        }
    }

    // GEMM2 A-fragments from own wave's hid rows (wave-local, no barrier)
    bf16x8 afr2[4];
    {
        int row = wrow + l15;
        #pragma unroll
        for (int kk = 0; kk < 4; ++kk)
            afr2[kk] = *(bf16x8*)&wfrag[row * 128 + ((kk * 32 + lk * 8) ^ ((row & 15) << 3))];
    }

    // GEMM2 + stats; z (bf16) back into own hid rows for coalesced store
    #pragma unroll
    for (int c = 0; c < 8; ++c) {
        float bv = b2[c * 16 + l15];
        f32x4 a = {bv, bv, bv, bv};
        #pragma unroll
        for (int kk = 0; kk < 4; ++kk) {
            bf16x8 w = *(bf16x8*)&wfrag[16384 + ((c * 4 + kk) * 64 + lane) * 8];
            a = __builtin_amdgcn_mfma_f32_16x16x32_bf16(afr2[kk], w, a, 0, 0, 0);
        }
        float s = 0.f, sq = 0.f;
        #pragma unroll
        for (int i = 0; i < 4; ++i) {
            int row = wrow + lk * 4 + i;
            int rg  = row0 + row;
            float v = a[i];
            bool ok = rg < N_NODES;
            if (ok) { s += v; sq += v * v; }
            wfrag[row * 128 + ((c * 16 + l15) ^ ((row & 15) << 3))] = ok ? f2bf(v) : (u16)0;
        }
        s  += __shfl_xor(s, 16);  s  += __shfl_xor(s, 32);
        sq += __shfl_xor(sq, 16); sq += __shfl_xor(sq, 32);
        if (lk == 0) {
            atomicAdd(&ssum[c * 16 + l15], s);
            atomicAdd(&ssq[c * 16 + l15], sq);
        }
    }

    // wave-local coalesced z store (own 16 rows, 4 x b128 per lane)
    #pragma unroll
    for (int j = 0; j < 4; ++j) {
        int chunk = j * 64 + lane;         // 0..255
        int rl  = chunk >> 4;
        int c8  = chunk & 15;
        int row = wrow + rl;
        int rg  = row0 + row;
        if (rg < N_NODES) {
            bf16x8 v = *(bf16x8*)&wfrag[row * 128 + ((c8 * 8) ^ ((row & 15) << 3))];
            *(bf16x8*)(Z + (long long)rg * 128 + c8 * 8) = v;
        }
    }
    __syncthreads();                       // (3) all LDS stat adds done
    if (tid < 128) {
        atomicAdd(&stats[tid], ssum[tid]);
        atomicAdd(&stats[128 + tid], ssq[tid]);
    }
}

// --------- graph pooling fused with BN+relu of layer-1 z ----------------------
__global__ __launch_bounds__(256)
void graph_pool_bn(const u16* __restrict__ z, const float* __restrict__ stats,
                   const float* __restrict__ gamma, const float* __restrict__ beta,
                   const int* __restrict__ gid, const float* __restrict__ pw,
                   float* __restrict__ out_nodes, float* __restrict__ out_pool)
{
    __shared__ float scs[128];
    __shared__ float shs[128];
    if (threadIdx.x < 128) {
        int c = threadIdx.x;
        float mu  = stats[c] * (1.f / N_NODES);
        float var = stats[128 + c] * (1.f / N_NODES) - mu * mu;
        float s   = gamma[c] * rsqrtf(var + BN_EPS);
        scs[c] = s;
        shs[c] = beta[c] - mu * s;
    }
    __syncthreads();

    int g    = blockIdx.x >> 2;            // POOL_SPLIT = 4
    int part = blockIdx.x & 3;

    int lo = 0, hi = N_NODES;
    while (lo < hi) { int m = (lo + hi) >> 1; if (gid[m] < g) lo = m + 1; else hi = m; }
    int start = lo;
    hi = N_NODES;
    while (lo < hi) { int m = (lo + hi) >> 1; if (gid[m] < g + 1) lo = m + 1; else hi = m; }
    int end = lo;

    int len  = end - start;
    int qlen = (len + 3) >> 2;
    int s = start + part * qlen;
    int e = min(end, s + qlen);

    const int t  = threadIdx.x;
    const int rg = t >> 5;
    const int c4 = t & 31;
    float4 sc4 = *(float4*)&scs[c4 * 4];
    float4 sh4 = *(float4*)&shs[c4 * 4];

    float4 acc = make_float4(0.f, 0.f, 0.f, 0.f);
    for (int r = s + rg; r < e; r += 8) {
        float w = pw[r];
        ushort4 hv = *((const ushort4*)(z + (long long)r * DIM) + c4);
        float4 v;
        v.x = fmaxf(bf2f(hv.x) * sc4.x + sh4.x, 0.f);
        v.y = fmaxf(bf2f(hv.y) * sc4.y + sh4.y, 0.f);
        v.z = fmaxf(bf2f(hv.z) * sc4.z + sh4.z, 0.f);
        v.w = fmaxf(bf2f(hv.w) * sc4.w + sh4.w, 0.f);
        *((float4*)(out_nodes + (long long)r * DIM) + c4) = v;
        acc.x += w * v.x; acc.y += w * v.y;
        acc.z += w * v.z; acc.w += w * v.w;
    }

    __shared__ float4 sd[256];
    sd[t] = acc;
    __syncthreads();
    if (t < 32) {
        float4 tot = sd[t];
        #pragma unroll
        for (int i = 1; i < 8; ++i) {
            float4 v = sd[i * 32 + t];
            tot.x += v.x; tot.y += v.y; tot.z += v.z; tot.w += v.w;
        }
        float* op = out_pool + g * DIM + t * 4;
        atomicAdd(op + 0, tot.x);
        atomicAdd(op + 1, tot.y);
        atomicAdd(op + 2, tot.z);
        atomicAdd(op + 3, tot.w);
    }
}

extern "C" void kernel_launch(void* const* d_in, const int* in_sizes, int n_in,
                              void* d_out, int out_size, void* d_ws, size_t ws_size,
                              hipStream_t stream)
{
    const float* x    = (const float*)d_in[0];
    const int*   esrc = (const int*)d_in[1];
    const int*   edst = (const int*)d_in[2];
    const float* ew   = (const float*)d_in[3];
    const int*   gid  = (const int*)d_in[4];
    const float* pw   = (const float*)d_in[5];
    const float* W1   = (const float*)d_in[6];
    const float* b1   = (const float*)d_in[7];
    const float* W2   = (const float*)d_in[8];
    const float* b2   = (const float*)d_in[9];
    const float* gam  = (const float*)d_in[10];
    const float* bet  = (const float*)d_in[11];

    float* out_pool  = (float*)d_out;                      // [512,128]
    float* out_nodes = (float*)d_out + NUM_GRAPHS * DIM;   // [50000,128]

    // ---- workspace layout ----
    const size_t NF = (size_t)N_NODES * DIM;
    char* w = (char*)d_ws;
    u32*   ed       = (u32*)w;        w += (size_t)N_EDGES * sizeof(u32);
    u16*   pooledBf = (u16*)w;        w += NF * sizeof(u16);   // aliases ed2cap
    u16*   zBf      = (u16*)w;        w += NF * sizeof(u16);
    u16*   hx       = (u16*)w;        w += NF * sizeof(u16);
    u16*   wt       = (u16*)w;        w += (size_t)4 * 128 * 128 * sizeof(u16);
    // contiguous zero region: stats0 | stats1 (512 words), then gCursor
    float* stats0   = (float*)w;      w += 256 * sizeof(float);
    float* stats1   = (float*)w;      w += 256 * sizeof(float);
    int*   gCursor  = (int*)w;        w += 256 * sizeof(int);
    int*   rowptr   = (int*)w;        w += (NBUCK * 256 + 64) * sizeof(int);

    // ed2cap (196 * 4608 * 8B = 7.2MB) aliases pooledBf's 12.8MB region:
    // written by partA range, consumed by partitionB, dead before first gather.
    uint2* ed2cap   = (uint2*)pooledBf;

    const int mlpGrid    = (N_NODES + MLP_ROWS - 1) / MLP_ROWS;  // 391
    const int gatherGrid = (N_NODES + 15) / 16;          // 3125

    // ---- pre-zero gCursor, then merged prep+partA, then partB ----
    fill_cursor_kernel<<<1, 256, 0, stream>>>(gCursor);
    prep_partA<<<RTOTAL, 512, 0, stream>>>(x, W1, W2, esrc, edst, ew,
                                           hx, wt, stats0, out_pool,
                                           gCursor, ed2cap);
    partitionB<<<NBUCK, 512, 0, stream>>>(ed2cap, gCursor, rowptr, ed);

    // ---- layer 0 ----
    gather_spmm<false><<<gatherGrid, 256, 0, stream>>>(hx, ed, rowptr, pooledBf,
                                                       nullptr, nullptr, nullptr);
    fused_mlp<<<mlpGrid, 512, 0, stream>>>(pooledBf, wt, b1, b2, zBf, stats0);

    // ---- layer 1 (BN of layer-0 z fused into the gather) ----
    gather_spmm<true><<<gatherGrid, 256, 0, stream>>>(zBf, ed, rowptr, pooledBf,
                                                      stats0, gam, bet);
    fused_mlp<<<mlpGrid, 512, 0, stream>>>(pooledBf, wt + 32768,
                                           b1 + DIM, b2 + DIM, zBf, stats1);

    // ---- BN(layer-1) + node output + graph pooling, all fused ----
    graph_pool_bn<<<NUM_GRAPHS * POOL_SPLIT, 256, 0, stream>>>(
        zBf, stats1, gam + DIM, bet + DIM, gid, pw, out_nodes, out_pool);
}